// Round 9
// baseline (35.005 us; speedup 1.0000x reference)
//
#include <hip/hip_runtime.h>
#include <stdint.h>

// Problem constants (from reference):
#define T_DIM 1024
#define B_DIM 8
#define C_DIM 1024
#define H_DIM 16
#define K_SZ  7
#define P_PAD 3
#define O_DIM (H_DIM * K_SZ)   // 112
#define TB    (T_DIM * B_DIM)  // 8192 rows

typedef __attribute__((ext_vector_type(8))) short bf16x8;  // 4 VGPRs, 8 bf16
typedef __attribute__((ext_vector_type(4))) float f32x4;
typedef __attribute__((ext_vector_type(2))) float f32x2;
typedef __attribute__((ext_vector_type(4))) uint32_t u32x4;

union FragU { uint32_t u[4]; bf16x8 v; };

// RNE fp32->bf16 pack of two floats into one dword (lo=a, hi=b)
__device__ inline uint32_t pk_bf16(float a, float b) {
  uint32_t ua = __float_as_uint(a), ub = __float_as_uint(b);
  ua += 0x7FFFu + ((ua >> 16) & 1u);
  ub += 0x7FFFu + ((ub >> 16) & 1u);
  return (ua >> 16) | (ub & 0xFFFF0000u);
}

__device__ inline bf16x8 load_bf16x8_cvt(const float* __restrict__ p) {
  float4 lo = *reinterpret_cast<const float4*>(p);
  float4 hi = *reinterpret_cast<const float4*>(p + 4);
  FragU f;
  f.u[0] = pk_bf16(lo.x, lo.y);
  f.u[1] = pk_bf16(lo.z, lo.w);
  f.u[2] = pk_bf16(hi.x, hi.y);
  f.u[3] = pk_bf16(hi.z, hi.w);
  return f.v;
}

// bf16-pair dword -> f32x2 {lo, hi}
__device__ inline f32x2 up2(uint32_t u) {
  f32x2 r;
  r.x = __uint_as_float(u << 16);
  r.y = __uint_as_float(u & 0xffff0000u);
  return r;
}

// Raw barrier: orders LDS producer->consumer WITHOUT draining vmcnt
// (prefetch loads / conv stores stay in flight across phases).
__device__ inline void bar_lds() {
  __builtin_amdgcn_sched_barrier(0);
  asm volatile("s_waitcnt lgkmcnt(0)" ::: "memory");
  __builtin_amdgcn_s_barrier();
  __builtin_amdgcn_sched_barrier(0);
}

// Single-dispatch fused kernel. 256 blocks x 1024 threads (16 waves, 1/CU).
// Block owns 32 t-rows (two 16-row windows W0,W1) for one b; x rows staged
// bf16 in a 32-slot LDS ring (slot = g&31, XOR-swizzle keyed g&7).
// W_lin fragments: each mfma wave (kh,nf) loads its 16 B-frags from Wl ONCE
// at kernel start (scattered, hidden under prologue) -> registers, reused
// for BOTH windows. No prep kernel, no workspace.
__global__ __launch_bounds__(1024, 4) void fused_pipe_kernel(
    const float* __restrict__ x, const float* __restrict__ Wl,
    const float* __restrict__ bl, const float* __restrict__ cb,
    float* __restrict__ out) {
  __shared__ char  ring[32 * 2048];     // 64KB: 32 bf16 rows, swizzled
  __shared__ float part[2][16][116];    // 14.5KB: per-K-half logits
  __shared__ float wsm[16][17][8];      // 8.7KB: softmax weights

  const int tid  = threadIdx.x;
  const int wv   = tid >> 6;            // 0..15
  const int lane = tid & 63;
  const int l15  = lane & 15;
  const int oct  = lane >> 4;

  // XCD swizzle: xcd owns 4 contiguous 32-row window-pairs for every b.
  const int bid = blockIdx.x;           // 0..255
  const int xcd = bid & 7;
  const int r8  = bid >> 3;             // 0..31
  const int b   = r8 >> 2;              // 0..7
  const int t0  = (xcd * 4 + (r8 & 3)) * 32;

  // ---- B-fragments: load once from fp32 W, convert, keep in regs ----
  const int kh = (wv >= 7) ? 1 : 0;
  const int nf = (wv < 14) ? (wv - kh * 7) : 0;
  bf16x8 bfr[16];
  if (wv < 14) {
    const float* __restrict__ wp =
        Wl + (size_t)(nf * 16 + l15) * C_DIM + kh * 512 + oct * 8;
#pragma unroll
    for (int s = 0; s < 16; ++s) bfr[s] = load_bf16x8_cvt(wp + s * 32);
  }

  auto stage_write = [&](int task, int gbase) {
    const int q   = task >> 7;
    const int c16 = task & 127;
    const int g   = min(max(gbase + q, 0), T_DIM - 1);
    const float* __restrict__ src =
        x + ((size_t)(g * B_DIM + b)) * C_DIM + c16 * 8;
    float4 v0 = *reinterpret_cast<const float4*>(src);
    float4 v1 = *reinterpret_cast<const float4*>(src + 4);
    FragU f;
    f.u[0] = pk_bf16(v0.x, v0.y);
    f.u[1] = pk_bf16(v0.z, v0.w);
    f.u[2] = pk_bf16(v1.x, v1.y);
    f.u[3] = pk_bf16(v1.z, v1.w);
    const int dst = (g & 31) * 2048 + ((c16 * 16) ^ ((g & 7) << 4));
    *reinterpret_cast<bf16x8*>(ring + dst) = f.v;
  };

  auto mfma_phase = [&](int wbase) {
    if (wv < 14) {
      f32x4 acc0 = (f32x4)(0.f), acc1 = (f32x4)(0.f);
      const int ag   = wbase + l15;
      const char* ab = ring + (ag & 31) * 2048;
      const int axor = (ag & 7) << 4;
#pragma unroll
      for (int s = 0; s < 8; ++s) {
        const int ksg = kh * 16 + s;
        bf16x8 a = *reinterpret_cast<const bf16x8*>(
            ab + ((ksg * 64 + oct * 16) ^ axor));
        acc0 = __builtin_amdgcn_mfma_f32_16x16x32_bf16(a, bfr[s], acc0, 0, 0, 0);
      }
#pragma unroll
      for (int s = 8; s < 16; ++s) {
        const int ksg = kh * 16 + s;
        bf16x8 a = *reinterpret_cast<const bf16x8*>(
            ab + ((ksg * 64 + oct * 16) ^ axor));
        acc1 = __builtin_amdgcn_mfma_f32_16x16x32_bf16(a, bfr[s], acc1, 0, 0, 0);
      }
      // D layout: col = lane&15 (W row), row = (lane>>4)*4 + reg (x row)
#pragma unroll
      for (int rr = 0; rr < 4; ++rr)
        part[kh][oct * 4 + rr][nf * 16 + l15] = acc0[rr] + acc1[rr];
    }
  };

  auto softmax_phase = [&]() {
    if (tid < 256) {
      const int row = tid >> 4;
      const int h   = tid & 15;
      float lg[7];
      float m = -1e30f;
#pragma unroll
      for (int j = 0; j < 7; ++j) {
        const int c = h * 7 + j;
        float s_ = part[0][row][c] + part[1][row][c] + bl[c];
        lg[j] = s_;
        m = fmaxf(m, s_);
      }
      float s = 0.f;
#pragma unroll
      for (int j = 0; j < 7; ++j) { lg[j] = __expf(lg[j] - m); s += lg[j]; }
      const float inv = 1.0f / s;
#pragma unroll
      for (int j = 0; j < 7; ++j) wsm[row][h][j] = lg[j] * inv;
    }
  };

  auto conv_phase = [&](int wbase) {
    const int row  = wv;               // one wave per output row
    const int gout = wbase + row;
    float* __restrict__ obase = out + ((size_t)(gout * B_DIM + b)) * C_DIM;
#pragma unroll
    for (int ii = 0; ii < 2; ++ii) {
      const int ch0  = ii * 512 + lane * 8;
      const int head = ch0 >> 6;
      float4 w0 = *reinterpret_cast<const float4*>(&wsm[row][head][0]);
      float4 w1 = *reinterpret_cast<const float4*>(&wsm[row][head][4]);
      float wj[7] = {w0.x, w0.y, w0.z, w0.w, w1.x, w1.y, w1.z};
#pragma unroll
      for (int j = 0; j < 7; ++j) {
        const int tp = gout + j - P_PAD;
        if (tp < 0 || tp >= T_DIM) wj[j] = 0.f;
      }
      f32x2 a0, a1, a2, a3;
      {
        float4 c0 = *reinterpret_cast<const float4*>(cb + ch0);
        float4 c1 = *reinterpret_cast<const float4*>(cb + ch0 + 4);
        a0.x = c0.x; a0.y = c0.y; a1.x = c0.z; a1.y = c0.w;
        a2.x = c1.x; a2.y = c1.y; a3.x = c1.z; a3.y = c1.w;
      }
#pragma unroll
      for (int j = 0; j < 7; ++j) {
        const int g = min(max(gout + j - P_PAD, 0), T_DIM - 1);
        const u32x4 d = *reinterpret_cast<const u32x4*>(
            ring + (g & 31) * 2048 + ((ch0 * 2) ^ ((g & 7) << 4)));
        f32x2 w2; w2.x = wj[j]; w2.y = wj[j];
        a0 += w2 * up2(d.x);    // f32x2 ops -> v_pk_fma_f32
        a1 += w2 * up2(d.y);
        a2 += w2 * up2(d.z);
        a3 += w2 * up2(d.w);
      }
      f32x4 o0, o1;
      o0[0] = a0.x; o0[1] = a0.y; o0[2] = a1.x; o0[3] = a1.y;
      o1[0] = a2.x; o1[1] = a2.y; o1[2] = a3.x; o1[3] = a3.y;
      __builtin_nontemporal_store(o0, reinterpret_cast<f32x4*>(obase + ch0));
      __builtin_nontemporal_store(o1, reinterpret_cast<f32x4*>(obase + ch0 + 4));
    }
  };

  // ---- prologue: stage rows t0-3 .. t0+18 (22 rows) ----
#pragma unroll
  for (int it = 0; it < 3; ++it) {
    const int task = tid + it * 1024;
    if (task < 22 * 128) stage_write(task, t0 - 3);
  }

  // ---- issue prefetch: rows t0+19 .. t0+34 (16 rows) into registers ----
  float4 pf0, pf1, pf2, pf3;
  {
    const int q0 = tid >> 7, c0_ = tid & 127;
    const int g0 = min(t0 + 19 + q0, T_DIM - 1);
    const float* __restrict__ s0 =
        x + ((size_t)(g0 * B_DIM + b)) * C_DIM + c0_ * 8;
    pf0 = *reinterpret_cast<const float4*>(s0);
    pf1 = *reinterpret_cast<const float4*>(s0 + 4);
    const int t2 = tid + 1024;
    const int q1 = t2 >> 7, c1_ = t2 & 127;
    const int g1 = min(t0 + 19 + q1, T_DIM - 1);
    const float* __restrict__ s1 =
        x + ((size_t)(g1 * B_DIM + b)) * C_DIM + c1_ * 8;
    pf2 = *reinterpret_cast<const float4*>(s1);
    pf3 = *reinterpret_cast<const float4*>(s1 + 4);
  }
  bar_lds();

  // ---- window 0 ----
  mfma_phase(t0);
  bar_lds();
  softmax_phase();
  bar_lds();
  conv_phase(t0);
  bar_lds();   // conv-W0 tap reads retired before ring slots are reused

  // ---- write prefetch into ring (slots dead after conv W0) ----
  {
    const int q0 = tid >> 7, c0_ = tid & 127;
    const int g0 = min(t0 + 19 + q0, T_DIM - 1);
    FragU f;
    f.u[0] = pk_bf16(pf0.x, pf0.y);
    f.u[1] = pk_bf16(pf0.z, pf0.w);
    f.u[2] = pk_bf16(pf1.x, pf1.y);
    f.u[3] = pk_bf16(pf1.z, pf1.w);
    *reinterpret_cast<bf16x8*>(
        ring + (g0 & 31) * 2048 + ((c0_ * 16) ^ ((g0 & 7) << 4))) = f.v;
    const int t2 = tid + 1024;
    const int q1 = t2 >> 7, c1_ = t2 & 127;
    const int g1 = min(t0 + 19 + q1, T_DIM - 1);
    FragU f2;
    f2.u[0] = pk_bf16(pf2.x, pf2.y);
    f2.u[1] = pk_bf16(pf2.z, pf2.w);
    f2.u[2] = pk_bf16(pf3.x, pf3.y);
    f2.u[3] = pk_bf16(pf3.z, pf3.w);
    *reinterpret_cast<bf16x8*>(
        ring + (g1 & 31) * 2048 + ((c1_ * 16) ^ ((g1 & 7) << 4))) = f2.v;
  }
  bar_lds();

  // ---- window 1 (B-fragments still in registers) ----
  mfma_phase(t0 + 16);
  bar_lds();
  softmax_phase();
  bar_lds();
  conv_phase(t0 + 16);
}

extern "C" void kernel_launch(void* const* d_in, const int* in_sizes, int n_in,
                              void* d_out, int out_size, void* d_ws, size_t ws_size,
                              hipStream_t stream) {
  const float* x  = (const float*)d_in[0];   // (T,B,C)
  const float* Wl = (const float*)d_in[1];   // (H*K, C)
  const float* bl = (const float*)d_in[2];   // (H*K,)
  const float* cb = (const float*)d_in[3];   // (C,)
  float* out = (float*)d_out;                // (T,B,C)

  fused_pipe_kernel<<<256, 1024, 0, stream>>>(x, Wl, bl, cb, out);
}

// Round 10
// 30.127 us; speedup vs baseline: 1.1619x; 1.1619x over previous
//
#include <hip/hip_runtime.h>
#include <stdint.h>

// Problem constants (from reference):
#define T_DIM 1024
#define B_DIM 8
#define C_DIM 1024
#define H_DIM 16
#define K_SZ  7
#define P_PAD 3
#define O_DIM (H_DIM * K_SZ)   // 112
#define TB    (T_DIM * B_DIM)  // 8192 rows

typedef __attribute__((ext_vector_type(8))) short bf16x8;  // 4 VGPRs, 8 bf16
typedef __attribute__((ext_vector_type(4))) float f32x4;

union FragU { uint32_t u[4]; bf16x8 v; };

// RNE fp32->bf16 pack of two floats into one dword (lo=a, hi=b)
__device__ inline uint32_t pk_bf16(float a, float b) {
  uint32_t ua = __float_as_uint(a), ub = __float_as_uint(b);
  ua += 0x7FFFu + ((ua >> 16) & 1u);
  ub += 0x7FFFu + ((ub >> 16) & 1u);
  return (ua >> 16) | (ub & 0xFFFF0000u);
}

__device__ inline bf16x8 cvt8(f32x4 lo, f32x4 hi) {
  FragU f;
  f.u[0] = pk_bf16(lo[0], lo[1]);
  f.u[1] = pk_bf16(lo[2], lo[3]);
  f.u[2] = pk_bf16(hi[0], hi[1]);
  f.u[3] = pk_bf16(hi[2], hi[3]);
  return f.v;
}

__device__ inline bf16x8 load_bf16x8_cvt(const float* __restrict__ p) {
  f32x4 lo = *reinterpret_cast<const f32x4*>(p);
  f32x4 hi = *reinterpret_cast<const f32x4*>(p + 4);
  return cvt8(lo, hi);
}

// async global->LDS, 16B per lane: LDS dest = wave-uniform base + lane*16,
// global src = per-lane address (pre-swizzled). Counted by vmcnt.
__device__ inline void gload_lds16(const void* g, void* l) {
  __builtin_amdgcn_global_load_lds(
      (const __attribute__((address_space(1))) uint32_t*)g,
      (__attribute__((address_space(3))) uint32_t*)l, 16, 0, 0);
}

__device__ inline void sbar() {
  __builtin_amdgcn_sched_barrier(0);
  __builtin_amdgcn_s_barrier();
  __builtin_amdgcn_sched_barrier(0);
}
// orders LDS producer->consumer without draining vmcnt
__device__ inline void bar_lds() {
  __builtin_amdgcn_sched_barrier(0);
  asm volatile("s_waitcnt lgkmcnt(0)" ::: "memory");
  __builtin_amdgcn_s_barrier();
  __builtin_amdgcn_sched_barrier(0);
}
__device__ inline void vm0() {
  __builtin_amdgcn_sched_barrier(0);
  asm volatile("s_waitcnt vmcnt(0)" ::: "memory");
  __builtin_amdgcn_sched_barrier(0);
}
__device__ inline void vm4() {
  __builtin_amdgcn_sched_barrier(0);
  asm volatile("s_waitcnt vmcnt(4)" ::: "memory");
  __builtin_amdgcn_sched_barrier(0);
}

// Kernel 0: build fragment-native bf16 W.
// Wf[((ks*7)+nf)*64 + lane] (16B) = W[nf*16+(lane&15)][ks*32+(lane>>4)*8 .. +7]
__global__ __launch_bounds__(256) void prep_wfrag_kernel(
    const float* __restrict__ Wl, uint16_t* __restrict__ Wf) {
  const int t  = blockIdx.x * 256 + threadIdx.x;  // 0..14335
  const int f  = t >> 6;
  const int l  = t & 63;
  const int ks = f / 7;
  const int nf = f - ks * 7;
  const int row = nf * 16 + (l & 15);
  const int kb  = ks * 32 + (l >> 4) * 8;
  bf16x8 v = load_bf16x8_cvt(Wl + (size_t)row * C_DIM + kb);
  *reinterpret_cast<bf16x8*>(Wf + (size_t)t * 8) = v;   // coalesced 16B/lane
}

// Fused kernel. 256 blocks x 1024 threads (16 waves, 1 block/CU).
// Block owns 32 t-rows (two 16-row windows) for one b. x staged as FP32 in a
// 32-slot LDS ring via global_load_lds (no staging VALU, no VGPR roundtrip).
// Swizzle: 16B-granule XOR key (t&7)<<4, applied on the per-lane GLOBAL source
// address (LDS dest linear) and again on every LDS read (involution).
// DMA schedule: prologue 22 rows; 10 rows (slots 19..28, disjoint from all W0
// readers) issued before barrier1, in flight across W0; 6 rows (slots
// 29,30,31,0,1,2) issued after conv W0 frees those slots, drained pre-mfma-W1.
template <bool PREPPED>
__global__ __launch_bounds__(1024) void fused_dma_kernel(
    const float* __restrict__ x, const float* __restrict__ Wl,
    const uint16_t* __restrict__ Wf, const float* __restrict__ bl,
    const float* __restrict__ cb, float* __restrict__ out) {
  __shared__ float ring[32 * 1024];     // 128KB: 32 fp32 rows, swizzled
  __shared__ float part[2][16][116];    // 14.5KB: per-K-half logits
  __shared__ float wsm[16][17][8];      // 8.7KB: softmax weights

  const int tid  = threadIdx.x;
  const int wv   = tid >> 6;            // 0..15
  const int lane = tid & 63;
  const int l15  = lane & 15;
  const int oct  = lane >> 4;

  // XCD swizzle: xcd owns 4 contiguous 32-row window-pairs for every b.
  const int bid = blockIdx.x;           // 0..255
  const int xcd = bid & 7;
  const int r8  = bid >> 3;             // 0..31
  const int b   = r8 >> 2;              // 0..7
  const int t0  = (xcd * 4 + (r8 & 3)) * 32;

  // stage logical row (t0-3+ridx) -> ring slot (logical&31), 4 DMA chunks
  auto stage_dma = [&](int ridx) {
    const int tlog = t0 - 3 + ridx;
    const int g    = min(max(tlog, 0), T_DIM - 1);
    const int slot = tlog & 31;
    const int key  = (tlog & 7) << 4;
    const char* __restrict__ rowp =
        (const char*)(x + ((size_t)(g * B_DIM + b)) * C_DIM);
    char* ldsrow = (char*)ring + slot * 4096;
#pragma unroll
    for (int q = 0; q < 4; ++q) {
      gload_lds16(rowp + (((q * 1024) + lane * 16) ^ key), ldsrow + q * 1024);
    }
  };

  auto mfma_phase = [&](int wbase) {
    if (wv < 14) {
      const int kh = (wv >= 7) ? 1 : 0;
      const int nf = wv - kh * 7;
      const int tA = wbase + l15;
      const char* rowb = (const char*)ring + (tA & 31) * 4096;
      const int key = (tA & 7) << 4;
      f32x4 acc0 = (f32x4)(0.f), acc1 = (f32x4)(0.f);
#pragma unroll
      for (int s = 0; s < 16; ++s) {
        const int ksg   = kh * 16 + s;
        const int inrow = ksg * 128 + oct * 32;
        f32x4 lo = *reinterpret_cast<const f32x4*>(rowb + (inrow ^ key));
        f32x4 hi = *reinterpret_cast<const f32x4*>(rowb + ((inrow + 16) ^ key));
        bf16x8 a = cvt8(lo, hi);
        bf16x8 bf;
        if (PREPPED)
          bf = *reinterpret_cast<const bf16x8*>(
              Wf + ((size_t)((ksg * 7 + nf) * 64) + lane) * 8);
        else
          bf = load_bf16x8_cvt(Wl + (size_t)(nf * 16 + l15) * C_DIM + ksg * 32 + oct * 8);
        if (s < 8) acc0 = __builtin_amdgcn_mfma_f32_16x16x32_bf16(a, bf, acc0, 0, 0, 0);
        else       acc1 = __builtin_amdgcn_mfma_f32_16x16x32_bf16(a, bf, acc1, 0, 0, 0);
      }
      // D layout: col = lane&15 (W row), row = (lane>>4)*4 + reg (x row)
#pragma unroll
      for (int rr = 0; rr < 4; ++rr)
        part[kh][oct * 4 + rr][nf * 16 + l15] = acc0[rr] + acc1[rr];
    }
  };

  auto softmax_phase = [&]() {
    if (tid < 256) {
      const int row = tid >> 4;
      const int h   = tid & 15;
      float lg[7];
      float m = -1e30f;
#pragma unroll
      for (int j = 0; j < 7; ++j) {
        const int c = h * 7 + j;
        float s_ = part[0][row][c] + part[1][row][c] + bl[c];
        lg[j] = s_;
        m = fmaxf(m, s_);
      }
      float s = 0.f;
#pragma unroll
      for (int j = 0; j < 7; ++j) { lg[j] = __expf(lg[j] - m); s += lg[j]; }
      const float inv = 1.0f / s;
#pragma unroll
      for (int j = 0; j < 7; ++j) wsm[row][h][j] = lg[j] * inv;
    }
  };

  auto conv_phase = [&](int wbase) {
    const int row  = wv;               // one wave per output row
    const int gout = wbase + row;
    const char* tbase[7];
    int tkey[7];
    float okf[7];
#pragma unroll
    for (int j = 0; j < 7; ++j) {
      const int tp = gout + j - P_PAD;
      okf[j] = (tp >= 0 && tp < T_DIM) ? 1.f : 0.f;
      const int g = min(max(tp, 0), T_DIM - 1);
      tbase[j] = (const char*)ring + (g & 31) * 4096;
      tkey[j]  = (g & 7) << 4;
    }
    float* __restrict__ obase = out + ((size_t)(gout * B_DIM + b)) * C_DIM;
#pragma unroll
    for (int k = 0; k < 4; ++k) {
      const int inrow = k * 1024 + lane * 16;   // thread: 4 ch (float4)
      const int ch    = k * 256 + lane * 4;
      const int head  = k * 4 + oct;
      float4 w0 = *reinterpret_cast<const float4*>(&wsm[row][head][0]);
      float4 w1 = *reinterpret_cast<const float4*>(&wsm[row][head][4]);
      const float wj[7] = {w0.x * okf[0], w0.y * okf[1], w0.z * okf[2],
                           w0.w * okf[3], w1.x * okf[4], w1.y * okf[5],
                           w1.z * okf[6]};
      f32x4 a = *reinterpret_cast<const f32x4*>(cb + ch);
#pragma unroll
      for (int j = 0; j < 7; ++j) {
        f32x4 d = *reinterpret_cast<const f32x4*>(tbase[j] + (inrow ^ tkey[j]));
        a += wj[j] * d;
      }
      __builtin_nontemporal_store(a, reinterpret_cast<f32x4*>(obase + ch));
    }
  };

  // ---- issue prologue DMA: logical rows idx 0..21 (t0-3 .. t0+18) ----
  for (int r = wv; r < 22; r += 16) stage_dma(r);   // wv<6: 2 rows; else 1
  // ---- issue prefetch A: rows idx 22..31 -> slots 19..28 (disjoint W0) ----
  if (wv >= 6) stage_dma(16 + wv);
  // drain own prologue, keep prefA in flight
  if (wv < 6) vm0(); else vm4();
  sbar();

  // ---- window 0 ----
  mfma_phase(t0);          // slots 0..15 (+ Wf loads force prefA drain by end)
  bar_lds();
  softmax_phase();
  bar_lds();
  conv_phase(t0);          // slots {29,30,31, 0..18}
  bar_lds();               // conv-W0 LDS reads retired

  // ---- prefetch B: rows idx 32..37 -> slots {29,30,31,0,1,2} (now dead) ----
  if (wv < 6) { stage_dma(32 + wv); vm0(); }
  sbar();                  // prefB in LDS; mfma W1 needs slots 16..31

  // ---- window 1 ----
  mfma_phase(t0 + 16);     // slots 16..31
  bar_lds();
  softmax_phase();
  bar_lds();
  conv_phase(t0 + 16);     // slots {13..31, 0,1,2}
}

extern "C" void kernel_launch(void* const* d_in, const int* in_sizes, int n_in,
                              void* d_out, int out_size, void* d_ws, size_t ws_size,
                              hipStream_t stream) {
  const float* x  = (const float*)d_in[0];   // (T,B,C)
  const float* Wl = (const float*)d_in[1];   // (H*K, C)
  const float* bl = (const float*)d_in[2];   // (H*K,)
  const float* cb = (const float*)d_in[3];   // (C,)
  float* out = (float*)d_out;                // (T,B,C)

  const bool prepped = ws_size >= 262144;    // 224KB frag-W, padded

  if (prepped) {
    uint16_t* wf = (uint16_t*)d_ws;
    prep_wfrag_kernel<<<(32 * 7 * 64) / 256, 256, 0, stream>>>(Wl, wf);
    fused_dma_kernel<true><<<256, 1024, 0, stream>>>(x, Wl, wf, bl, cb, out);
  } else {
    fused_dma_kernel<false><<<256, 1024, 0, stream>>>(x, Wl, nullptr, bl, cb, out);
  }
}